// Round 13
// baseline (361.507 us; speedup 1.0000x reference)
//
#include <hip/hip_runtime.h>
#include <hip/hip_bf16.h>
#include <type_traits>

#define NN 100000
#define NE 800000
#define HD 128
#define BN_EPS 1e-5f

typedef __bf16 bf16x8 __attribute__((ext_vector_type(8)));
typedef float  f32x4  __attribute__((ext_vector_type(4)));
typedef float  f32x2  __attribute__((ext_vector_type(2)));

// ---------------- CSR build ----------------

// histogram + save each edge's rank within its dst bucket (coalesced write)
__global__ __launch_bounds__(256) void count_k(const int* __restrict__ ei, int* __restrict__ count,
                                               int* __restrict__ rank) {
    int e = blockIdx.x * 256 + threadIdx.x;
    if (e < NE) rank[e] = atomicAdd(&count[ei[NE + e]], 1);
}

// BN affine precompute: A = g*rsqrt(v+eps), B = b - m*A  (both layers in one block)
__global__ __launch_bounds__(256) void bnpre_k(const float* __restrict__ g0, const float* __restrict__ b0,
                                               const float* __restrict__ m0, const float* __restrict__ v0,
                                               const float* __restrict__ g1, const float* __restrict__ b1,
                                               const float* __restrict__ m1, const float* __restrict__ v1,
                                               float* __restrict__ A0, float* __restrict__ B0,
                                               float* __restrict__ A1, float* __restrict__ B1) {
    int t = threadIdx.x;
    if (t < 128) {
        float a = g0[t] * rsqrtf(v0[t] + BN_EPS);
        A0[t] = a; B0[t] = b0[t] - m0[t] * a;
    } else {
        int u = t - 128;
        float a = g1[u] * rsqrtf(v1[u] + BN_EPS);
        A1[u] = a; B1[u] = b1[u] - m1[u] * a;
    }
}

// transpose W0/W1/W2 [k][n] fp32 -> WT [n][k] bf16 (global, staged to LDS by gemm)
__global__ __launch_bounds__(256) void prepw_k(const float* __restrict__ W0, const float* __restrict__ W1,
                                               const float* __restrict__ W2, __bf16* __restrict__ WT) {
    const float* Ws[3] = {W0, W1, W2};
    const float* W = Ws[blockIdx.x];
    __bf16* T = WT + blockIdx.x * (HD * HD);
    int tid = threadIdx.x;
    #pragma unroll
    for (int it = 0; it < 64; ++it) {
        int idx = it * 256 + tid;          // idx = n*128 + k (writes coalesced)
        int n = idx >> 7, k = idx & 127;
        T[idx] = (__bf16)W[k * HD + n];
    }
}

// block-level exclusive scan of count + per-node norm terms
__global__ __launch_bounds__(256) void scan1_k(const int* __restrict__ count,
                                               int* __restrict__ rp, int* __restrict__ bsums,
                                               float* __restrict__ dis, float* __restrict__ selfn) {
    __shared__ int sm[256];
    int tid = threadIdx.x;
    int i = blockIdx.x * 256 + tid;
    int v = (i < NN) ? count[i] : 0;
    if (i < NN) {
        float deg = (float)v + 1.0f;
        float di = rsqrtf(deg);
        dis[i] = di;
        selfn[i] = di * di;
    }
    sm[tid] = v; __syncthreads();
    for (int off = 1; off < 256; off <<= 1) {
        int t = (tid >= off) ? sm[tid - off] : 0;
        __syncthreads();
        sm[tid] += t;
        __syncthreads();
    }
    if (i < NN) rp[i] = sm[tid] - v;           // exclusive within block
    if (tid == 255) bsums[blockIdx.x] = sm[tid];
}

// fused scan2+scan3: every block redundantly reduces bsums[0..blockIdx)
__global__ __launch_bounds__(256) void scan23_k(int* __restrict__ rp, const int* __restrict__ bsums, int nb) {
    __shared__ int sm[256];
    int tid = threadIdx.x;
    int b = blockIdx.x;
    int partial = 0;
    for (int i = tid; i < b; i += 256) partial += bsums[i];
    sm[tid] = partial; __syncthreads();
    #pragma unroll
    for (int off = 128; off > 0; off >>= 1) {
        if (tid < off) sm[tid] += sm[tid + off];
        __syncthreads();
    }
    int prefix = sm[0];
    int i = b * 256 + tid;
    if (i < NN) rp[i] += prefix;
    if (i == 0) rp[NN] = NE;
}

// scatter edges into CSR as packed (src, weight_bits); no atomics (rank precomputed)
__global__ __launch_bounds__(256) void scatter_k(const int* __restrict__ ei, const int* __restrict__ rp,
                                                 const int* __restrict__ rank, const float* __restrict__ dis,
                                                 uint2* __restrict__ edges) {
    int e = blockIdx.x * 256 + threadIdx.x;
    if (e >= NE) return;
    int s = ei[e], d = ei[NE + e];
    int pos = rp[d] + rank[e];
    edges[pos] = make_uint2((unsigned)s, __float_as_uint(dis[s] * dis[d]));
}

// ---------------- degree-sort permutation (equalize loop trip counts) ----------
// bin = min(deg,63). 3 passes: LDS-aggregated histogram (+ per-node rank within
// bin), 1-wave exclusive scan of 64 bins, scatter node ids.

__global__ __launch_bounds__(256) void dhist_k(const int* __restrict__ count, int* __restrict__ rank2,
                                               int* __restrict__ gcnt) {
    __shared__ int lh[64];
    __shared__ int lbase[64];
    int tid = threadIdx.x;
    if (tid < 64) lh[tid] = 0;
    __syncthreads();
    int i = blockIdx.x * 256 + tid;
    int bin = 0, myrank = 0;
    if (i < NN) {
        bin = min(count[i], 63);
        myrank = atomicAdd(&lh[bin], 1);
    }
    __syncthreads();
    if (tid < 64) lbase[tid] = lh[tid] ? atomicAdd(&gcnt[tid], lh[tid]) : 0;
    __syncthreads();
    if (i < NN) rank2[i] = lbase[bin] + myrank;
}

__global__ __launch_bounds__(64) void dscan_k(const int* __restrict__ gcnt, int* __restrict__ binoff) {
    // single wave: exclusive scan of 64 bins via shuffles
    int t = threadIdx.x;
    int v = gcnt[t];
    int x = v;
    #pragma unroll
    for (int off = 1; off < 64; off <<= 1) {
        int y = __shfl_up(x, off);
        if (t >= off) x += y;
    }
    binoff[t] = x - v;   // exclusive
}

__global__ __launch_bounds__(256) void dperm_k(const int* __restrict__ count, const int* __restrict__ rank2,
                                               const int* __restrict__ binoff, int* __restrict__ perm) {
    int i = blockIdx.x * 256 + threadIdx.x;
    if (i >= NN) return;
    int bin = min(count[i], 63);
    perm[binoff[bin] + rank2[i]] = i;
}

// ---------------- GEMM: [N,128] (fp32 or bf16) @ WT[n][k] bf16 -> bf16 ----------------

#define WROW 136   // padded LDS row stride (halfwords); 272 B = 17*16, b128-aligned

template <typename T>
__global__ __launch_bounds__(256, 4) void gemm128_k(const T* __restrict__ A, const __bf16* __restrict__ WTg,
                                                    __bf16* __restrict__ HW) {
    __shared__ __bf16 WL[128 * WROW];
    const int tid = threadIdx.x;
    const int wid  = __builtin_amdgcn_readfirstlane(tid >> 6);
    const int lane = tid & 63;
    const int m = lane & 15, quad = lane >> 4;
    const int row_base = blockIdx.x * 64 + wid * 16;

    // prefetch this lane's 4 A-fragments (k = ks*32 + quad*8) before the barrier
    int r = row_base + m;
    if (r >= NN) r = NN - 1;
    bf16x8 afr[4];
    if constexpr (std::is_same<T, float>::value) {
        const float4* ap = (const float4*)(A + (size_t)r * HD);
        #pragma unroll
        for (int ks = 0; ks < 4; ++ks) {
            float4 x0 = ap[ks * 8 + quad * 2], x1 = ap[ks * 8 + quad * 2 + 1];
            bf16x8 a;
            a[0] = (__bf16)x0.x; a[1] = (__bf16)x0.y; a[2] = (__bf16)x0.z; a[3] = (__bf16)x0.w;
            a[4] = (__bf16)x1.x; a[5] = (__bf16)x1.y; a[6] = (__bf16)x1.z; a[7] = (__bf16)x1.w;
            afr[ks] = a;
        }
    } else {
        const bf16x8* ap = (const bf16x8*)(A + (size_t)r * HD);
        #pragma unroll
        for (int ks = 0; ks < 4; ++ks) afr[ks] = ap[ks * 4 + quad];
    }

    // stage WT -> LDS: 2048 b128 chunks (128 rows x 16 chunks of 8 halfwords)
    #pragma unroll
    for (int it = 0; it < 8; ++it) {
        int id = it * 256 + tid;          // chunk id
        int n = id >> 4, c = id & 15;     // row, 16B-chunk within row
        *(uint4*)&WL[n * WROW + c * 8] = *(const uint4*)(WTg + n * HD + c * 8);
    }
    __syncthreads();

    f32x4 acc[8];
    #pragma unroll
    for (int ct = 0; ct < 8; ++ct) acc[ct] = (f32x4){0.f, 0.f, 0.f, 0.f};

    #pragma unroll
    for (int ks = 0; ks < 4; ++ks) {
        const int k0 = ks * 32 + quad * 8;
        #pragma unroll
        for (int ct = 0; ct < 8; ++ct) {
            bf16x8 bfr = *(const bf16x8*)&WL[(ct * 16 + m) * WROW + k0];
            acc[ct] = __builtin_amdgcn_mfma_f32_16x16x32_bf16(afr[ks], bfr, acc[ct], 0, 0, 0);
        }
    }

    #pragma unroll
    for (int ct = 0; ct < 8; ++ct)
        #pragma unroll
        for (int rr = 0; rr < 4; ++rr) {
            int row = row_base + quad * 4 + rr;
            if (row < NN) HW[(size_t)row * HD + ct * 16 + m] = (__bf16)acc[ct][rr];
        }
}

// ---------------- pull aggregation + epilogue ----------------
// 4 nodes per wave (degree-sorted via perm), 16 lanes per node; 4-deep
// software pipeline; packed float2 accumulation (v_pk_fma_f32).
// MODE 0: hb = relu(z); MODE 1: hb = relu(z*A+B) + hb; MODE 2: MODE-1 then
// in-register W3 projection -> hw3.

__device__ __forceinline__ void acc8p(f32x2* acc, uint4 rv, float wt) {
    f32x2 w2 = {wt, wt};
    f32x2 x0 = {__uint_as_float(rv.x << 16), __uint_as_float(rv.x & 0xffff0000u)};
    f32x2 x1 = {__uint_as_float(rv.y << 16), __uint_as_float(rv.y & 0xffff0000u)};
    f32x2 x2 = {__uint_as_float(rv.z << 16), __uint_as_float(rv.z & 0xffff0000u)};
    f32x2 x3 = {__uint_as_float(rv.w << 16), __uint_as_float(rv.w & 0xffff0000u)};
    acc[0] = __builtin_elementwise_fma(x0, w2, acc[0]);
    acc[1] = __builtin_elementwise_fma(x1, w2, acc[1]);
    acc[2] = __builtin_elementwise_fma(x2, w2, acc[2]);
    acc[3] = __builtin_elementwise_fma(x3, w2, acc[3]);
}

__device__ __forceinline__ void unpack8(uint4 rv, float* f) {
    f[0] = __uint_as_float(rv.x << 16);         f[1] = __uint_as_float(rv.x & 0xffff0000u);
    f[2] = __uint_as_float(rv.y << 16);         f[3] = __uint_as_float(rv.y & 0xffff0000u);
    f[4] = __uint_as_float(rv.z << 16);         f[5] = __uint_as_float(rv.z & 0xffff0000u);
    f[6] = __uint_as_float(rv.w << 16);         f[7] = __uint_as_float(rv.w & 0xffff0000u);
}

template <int MODE>
__global__ __launch_bounds__(256) void agg_k(const __bf16* __restrict__ hw, const int* __restrict__ rp,
                                             const uint2* __restrict__ edges, const int* __restrict__ perm,
                                             const float* __restrict__ selfn, const float* __restrict__ bias,
                                             const float* __restrict__ bnA, const float* __restrict__ bnB,
                                             __bf16* __restrict__ hb, const float* __restrict__ W3,
                                             float2* __restrict__ hw3) {
    const int lane = threadIdx.x & 63;
    const int wid  = threadIdx.x >> 6;
    const int grp  = lane >> 4;     // node within the wave
    const int m    = lane & 15;     // 16B chunk within the row (channels 8m..8m+7)
    const int n = perm[blockIdx.x * 16 + wid * 4 + grp];   // NN = 6250*16 exactly
    const int c0 = m * 8;
    const int L = NE - 1;

    const int e0 = rp[n], e1 = rp[n + 1];

    // issue long-latency independent loads first: self row, residual row
    const float sn = selfn[n];
    uint4 rv_self = *(const uint4*)(hw + ((size_t)n << 7) + c0);
    __bf16* hbp = hb + ((size_t)n << 7) + c0;
    uint4 rv_prev;
    if (MODE != 0) rv_prev = *(const uint4*)hbp;

    f32x2 acc2[4];
    #pragma unroll
    for (int j = 0; j < 4; ++j) acc2[j] = (f32x2){0.f, 0.f};

    // 4-deep pipelined gather loop
    int e = e0;
    int cnt = e1 - e0;
    uint2 edA = edges[min(e,     L)];
    uint2 edB = edges[min(e + 1, L)];
    uint2 edC = edges[min(e + 2, L)];
    uint2 edD = edges[min(e + 3, L)];
    while (cnt >= 4) {
        uint4 r0 = *(const uint4*)(hw + ((size_t)edA.x << 7) + c0);
        uint4 r1 = *(const uint4*)(hw + ((size_t)edB.x << 7) + c0);
        uint4 r2 = *(const uint4*)(hw + ((size_t)edC.x << 7) + c0);
        uint4 r3 = *(const uint4*)(hw + ((size_t)edD.x << 7) + c0);
        uint2 nA = edges[min(e + 4, L)];
        uint2 nB = edges[min(e + 5, L)];
        uint2 nC = edges[min(e + 6, L)];
        uint2 nD = edges[min(e + 7, L)];
        acc8p(acc2, r0, __uint_as_float(edA.y));
        acc8p(acc2, r1, __uint_as_float(edB.y));
        acc8p(acc2, r2, __uint_as_float(edC.y));
        acc8p(acc2, r3, __uint_as_float(edD.y));
        edA = nA; edB = nB; edC = nC; edD = nD;
        e += 4; cnt -= 4;
    }
    if (cnt >= 2) {
        uint4 r0 = *(const uint4*)(hw + ((size_t)edA.x << 7) + c0);
        uint4 r1 = *(const uint4*)(hw + ((size_t)edB.x << 7) + c0);
        acc8p(acc2, r0, __uint_as_float(edA.y));
        acc8p(acc2, r1, __uint_as_float(edB.y));
        edA = edC;           // for the cnt==3 tail
        cnt -= 2;
    }
    if (cnt == 1) {
        uint4 rv = *(const uint4*)(hw + ((size_t)edA.x << 7) + c0);
        acc8p(acc2, rv, __uint_as_float(edA.y));
    }
    acc8p(acc2, rv_self, sn);   // self-loop

    float acc[8] = {acc2[0][0], acc2[0][1], acc2[1][0], acc2[1][1],
                    acc2[2][0], acc2[2][1], acc2[3][0], acc2[3][1]};

    float4 bs0 = *(const float4*)(bias + c0);
    float4 bs1 = *(const float4*)(bias + c0 + 4);
    float z[8] = {acc[0] + bs0.x, acc[1] + bs0.y, acc[2] + bs0.z, acc[3] + bs0.w,
                  acc[4] + bs1.x, acc[5] + bs1.y, acc[6] + bs1.z, acc[7] + bs1.w};

    if (MODE == 0) {
        bf16x8 v;
        #pragma unroll
        for (int j = 0; j < 8; ++j) v[j] = (__bf16)fmaxf(z[j], 0.f);
        *(bf16x8*)hbp = v;
    } else {
        float4 a0v = *(const float4*)(bnA + c0), a1v = *(const float4*)(bnA + c0 + 4);
        float4 b0v = *(const float4*)(bnB + c0), b1v = *(const float4*)(bnB + c0 + 4);
        float Af[8] = {a0v.x, a0v.y, a0v.z, a0v.w, a1v.x, a1v.y, a1v.z, a1v.w};
        float Bf[8] = {b0v.x, b0v.y, b0v.z, b0v.w, b1v.x, b1v.y, b1v.z, b1v.w};
        float pr[8];
        unpack8(rv_prev, pr);
        float hn[8];
        #pragma unroll
        for (int j = 0; j < 8; ++j)
            hn[j] = fmaxf(fmaf(z[j], Af[j], Bf[j]), 0.f) + pr[j];

        if (MODE == 1) {
            bf16x8 v;
            #pragma unroll
            for (int j = 0; j < 8; ++j) v[j] = (__bf16)hn[j];
            *(bf16x8*)hbp = v;
        } else {
            // fused output projection: hw3[n] = hn . W3  (W3 is [128,2] row-major)
            float4 w0 = *(const float4*)(W3 + c0 * 2);
            float4 w1 = *(const float4*)(W3 + c0 * 2 + 4);
            float4 w2 = *(const float4*)(W3 + c0 * 2 + 8);
            float4 w3v = *(const float4*)(W3 + c0 * 2 + 12);
            float p0 = hn[0] * w0.x + hn[1] * w0.z + hn[2] * w1.x + hn[3] * w1.z
                     + hn[4] * w2.x + hn[5] * w2.z + hn[6] * w3v.x + hn[7] * w3v.z;
            float p1 = hn[0] * w0.y + hn[1] * w0.w + hn[2] * w1.y + hn[3] * w1.w
                     + hn[4] * w2.y + hn[5] * w2.w + hn[6] * w3v.y + hn[7] * w3v.w;
            // reduce within the 16-lane group (xor < 16 stays inside the group)
            #pragma unroll
            for (int o = 1; o < 16; o <<= 1) {
                p0 += __shfl_xor(p0, o);
                p1 += __shfl_xor(p1, o);
            }
            if (m == 0) hw3[n] = make_float2(p0, p1);
        }
    }
}

// ---------------- final: aggregate hw3 + log_softmax (degree-sorted) ----------------

__global__ __launch_bounds__(256) void final_k(const float2* __restrict__ hw3, const int* __restrict__ rp,
                                               const uint2* __restrict__ edges, const int* __restrict__ perm,
                                               const float* __restrict__ selfn, const float* __restrict__ b3,
                                               float* __restrict__ out) {
    int i = blockIdx.x * 256 + threadIdx.x;
    if (i >= NN) return;
    int n = perm[i];
    float a0 = 0.f, a1 = 0.f;
    int e1 = rp[n + 1];
    for (int e = rp[n]; e < e1; ++e) {
        uint2 ed = edges[e];
        float w = __uint_as_float(ed.y);
        float2 v = hw3[ed.x];
        a0 = fmaf(w, v.x, a0);
        a1 = fmaf(w, v.y, a1);
    }
    float sn = selfn[n];
    float2 hv = hw3[n];
    float z0 = a0 + sn * hv.x + b3[0];
    float z1 = a1 + sn * hv.y + b3[1];
    float mx = fmaxf(z0, z1);
    float l = mx + logf(expf(z0 - mx) + expf(z1 - mx));
    out[n * 2 + 0] = z0 - l;
    out[n * 2 + 1] = z1 - l;
}

// ---------------- launch ----------------

extern "C" void kernel_launch(void* const* d_in, const int* in_sizes, int n_in,
                              void* d_out, int out_size, void* d_ws, size_t ws_size,
                              hipStream_t stream) {
    (void)in_sizes; (void)n_in; (void)out_size; (void)ws_size;

    const float* x   = (const float*)d_in[0];
    const int*   ei  = (const int*)d_in[1];
    const float* W0  = (const float*)d_in[2];
    const float* b0  = (const float*)d_in[3];
    const float* W1  = (const float*)d_in[4];
    const float* b1  = (const float*)d_in[5];
    const float* W2  = (const float*)d_in[6];
    const float* b2  = (const float*)d_in[7];
    const float* W3  = (const float*)d_in[8];
    const float* b3  = (const float*)d_in[9];
    const float* bn0g = (const float*)d_in[10];
    const float* bn0b = (const float*)d_in[11];
    const float* bn0m = (const float*)d_in[12];
    const float* bn0v = (const float*)d_in[13];
    const float* bn1g = (const float*)d_in[14];
    const float* bn1b = (const float*)d_in[15];
    const float* bn1m = (const float*)d_in[16];
    const float* bn1v = (const float*)d_in[17];
    float* out = (float*)d_out;

    char* p = (char*)d_ws;
    auto alloc = [&](size_t bytes) -> void* {
        void* r = (void*)p;
        p += (bytes + 255) & ~(size_t)255;
        return r;
    };
    __bf16*  hb    = (__bf16*)alloc((size_t)NN * HD * 2);   // h in bf16
    __bf16*  hw    = (__bf16*)alloc((size_t)NN * HD * 2);
    float2*  hw3   = (float2*)alloc((size_t)NN * 8);
    float*   dis   = (float*)alloc((size_t)NN * 4);
    float*   selfn = (float*)alloc((size_t)NN * 4);
    int*     count = (int*)alloc((size_t)NN * 4);
    int*     gcnt  = (int*)alloc((size_t)64 * 4);   // adjacent to count: one memset covers both
    int*     rp    = (int*)alloc((size_t)(NN + 1) * 4);
    uint2*   edges = (uint2*)alloc((size_t)NE * 8);
    int*     rank  = (int*)alloc((size_t)NE * 4);
    int*     rank2 = (int*)alloc((size_t)NN * 4);
    int*     perm  = (int*)alloc((size_t)NN * 4);
    int*     binoff= (int*)alloc((size_t)64 * 4);
    int*     bsums = (int*)alloc((size_t)512 * 4);
    float*   bnA0  = (float*)alloc(128 * 4);
    float*   bnB0  = (float*)alloc(128 * 4);
    float*   bnA1  = (float*)alloc(128 * 4);
    float*   bnB1  = (float*)alloc(128 * 4);
    __bf16*  WT    = (__bf16*)alloc((size_t)3 * HD * HD * 2);  // transposed bf16 weights

    const int NB_E = (NE + 255) / 256;   // 3125
    const int NB_N = (NN + 255) / 256;   // 391
    const int NB_G = (NN + 63) / 64;     // 1563 (GEMM: 64 rows/block)
    const int NB_A = (NN + 15) / 16;     // 6250 (agg: 16 nodes per block)

    // zero count (NN) and gcnt (64) in one memset (gcnt allocated right after count)
    hipMemsetAsync(count, 0, (size_t)NN * 4 + 256, stream);

    count_k<<<NB_E, 256, 0, stream>>>(ei, count, rank);
    prepw_k<<<3, 256, 0, stream>>>(W0, W1, W2, WT);
    bnpre_k<<<1, 256, 0, stream>>>(bn0g, bn0b, bn0m, bn0v, bn1g, bn1b, bn1m, bn1v,
                                   bnA0, bnB0, bnA1, bnB1);
    scan1_k<<<NB_N, 256, 0, stream>>>(count, rp, bsums, dis, selfn);
    scan23_k<<<NB_N, 256, 0, stream>>>(rp, bsums, NB_N);
    scatter_k<<<NB_E, 256, 0, stream>>>(ei, rp, rank, dis, edges);
    // degree-sort permutation
    dhist_k<<<NB_N, 256, 0, stream>>>(count, rank2, gcnt);
    dscan_k<<<1, 64, 0, stream>>>(gcnt, binoff);
    dperm_k<<<NB_N, 256, 0, stream>>>(count, rank2, binoff, perm);

    // layer 0: hb = relu(conv(x, W0, b0))
    gemm128_k<float><<<NB_G, 256, 0, stream>>>(x, WT, hw);
    agg_k<0><<<NB_A, 256, 0, stream>>>(hw, rp, edges, perm, selfn, b0,
                                       nullptr, nullptr, hb, nullptr, nullptr);
    // layer 1: hb = relu(bn0(conv(hb, W1, b1))) + hb
    gemm128_k<__bf16><<<NB_G, 256, 0, stream>>>(hb, WT + HD * HD, hw);
    agg_k<1><<<NB_A, 256, 0, stream>>>(hw, rp, edges, perm, selfn, b1,
                                       bnA0, bnB0, hb, nullptr, nullptr);
    // layer 2 (+ fused W3 projection): hw3 = (relu(bn1(conv(hb, W2, b2))) + hb) @ W3
    gemm128_k<__bf16><<<NB_G, 256, 0, stream>>>(hb, WT + 2 * HD * HD, hw);
    agg_k<2><<<NB_A, 256, 0, stream>>>(hw, rp, edges, perm, selfn, b2,
                                       bnA1, bnB1, hb, W3, hw3);
    // final aggregation + log_softmax
    final_k<<<NB_N, 256, 0, stream>>>(hw3, rp, edges, perm, selfn, b3, out);
}

// Round 14
// 339.878 us; speedup vs baseline: 1.0636x; 1.0636x over previous
//
#include <hip/hip_runtime.h>
#include <hip/hip_bf16.h>
#include <type_traits>

#define NN 100000
#define NE 800000
#define HD 128
#define BN_EPS 1e-5f

typedef __bf16 bf16x8 __attribute__((ext_vector_type(8)));
typedef float  f32x4  __attribute__((ext_vector_type(4)));
typedef float  f32x2  __attribute__((ext_vector_type(2)));

// ---------------- CSR build ----------------

// histogram + save each edge's rank within its dst bucket (coalesced write)
__global__ __launch_bounds__(256) void count_k(const int* __restrict__ ei, int* __restrict__ count,
                                               int* __restrict__ rank) {
    int e = blockIdx.x * 256 + threadIdx.x;
    if (e < NE) rank[e] = atomicAdd(&count[ei[NE + e]], 1);
}

// fused weight transpose (blocks 0-2) + BN affine precompute (block 3)
__global__ __launch_bounds__(256) void prep_k(const float* __restrict__ W0, const float* __restrict__ W1,
                                              const float* __restrict__ W2, __bf16* __restrict__ WT,
                                              const float* __restrict__ g0, const float* __restrict__ b0,
                                              const float* __restrict__ m0, const float* __restrict__ v0,
                                              const float* __restrict__ g1, const float* __restrict__ b1,
                                              const float* __restrict__ m1, const float* __restrict__ v1,
                                              float* __restrict__ A0, float* __restrict__ B0,
                                              float* __restrict__ A1, float* __restrict__ B1) {
    int tid = threadIdx.x;
    if (blockIdx.x < 3) {
        const float* Ws[3] = {W0, W1, W2};
        const float* W = Ws[blockIdx.x];
        __bf16* T = WT + blockIdx.x * (HD * HD);
        #pragma unroll
        for (int it = 0; it < 64; ++it) {
            int idx = it * 256 + tid;          // idx = n*128 + k (writes coalesced)
            int n = idx >> 7, k = idx & 127;
            T[idx] = (__bf16)W[k * HD + n];
        }
    } else {
        if (tid < 128) {
            float a = g0[tid] * rsqrtf(v0[tid] + BN_EPS);
            A0[tid] = a; B0[tid] = b0[tid] - m0[tid] * a;
        } else {
            int u = tid - 128;
            float a = g1[u] * rsqrtf(v1[u] + BN_EPS);
            A1[u] = a; B1[u] = b1[u] - m1[u] * a;
        }
    }
}

// block-level exclusive scan of count + per-node norm terms
__global__ __launch_bounds__(256) void scan1_k(const int* __restrict__ count,
                                               int* __restrict__ rp, int* __restrict__ bsums,
                                               float* __restrict__ dis, float* __restrict__ selfn) {
    __shared__ int sm[256];
    int tid = threadIdx.x;
    int i = blockIdx.x * 256 + tid;
    int v = (i < NN) ? count[i] : 0;
    if (i < NN) {
        float deg = (float)v + 1.0f;
        float di = rsqrtf(deg);
        dis[i] = di;
        selfn[i] = di * di;
    }
    sm[tid] = v; __syncthreads();
    for (int off = 1; off < 256; off <<= 1) {
        int t = (tid >= off) ? sm[tid - off] : 0;
        __syncthreads();
        sm[tid] += t;
        __syncthreads();
    }
    if (i < NN) rp[i] = sm[tid] - v;           // exclusive within block
    if (tid == 255) bsums[blockIdx.x] = sm[tid];
}

// fused scan2+scan3: every block redundantly reduces bsums[0..blockIdx)
__global__ __launch_bounds__(256) void scan23_k(int* __restrict__ rp, const int* __restrict__ bsums, int nb) {
    __shared__ int sm[256];
    int tid = threadIdx.x;
    int b = blockIdx.x;
    int partial = 0;
    for (int i = tid; i < b; i += 256) partial += bsums[i];
    sm[tid] = partial; __syncthreads();
    #pragma unroll
    for (int off = 128; off > 0; off >>= 1) {
        if (tid < off) sm[tid] += sm[tid + off];
        __syncthreads();
    }
    int prefix = sm[0];
    int i = b * 256 + tid;
    if (i < NN) rp[i] += prefix;
    if (i == 0) rp[NN] = NE;
}

// scatter edges into CSR as packed (src, weight_bits); no atomics (rank precomputed)
__global__ __launch_bounds__(256) void scatter_k(const int* __restrict__ ei, const int* __restrict__ rp,
                                                 const int* __restrict__ rank, const float* __restrict__ dis,
                                                 uint2* __restrict__ edges) {
    int e = blockIdx.x * 256 + threadIdx.x;
    if (e >= NE) return;
    int s = ei[e], d = ei[NE + e];
    int pos = rp[d] + rank[e];
    edges[pos] = make_uint2((unsigned)s, __float_as_uint(dis[s] * dis[d]));
}

// ---------------- GEMM: [N,128] (fp32 or bf16) @ WT[n][k] bf16 -> bf16 ----------------

#define WROW 136   // padded LDS row stride (halfwords); 272 B = 17*16, b128-aligned

template <typename T>
__global__ __launch_bounds__(256, 4) void gemm128_k(const T* __restrict__ A, const __bf16* __restrict__ WTg,
                                                    __bf16* __restrict__ HW) {
    __shared__ __bf16 WL[128 * WROW];
    const int tid = threadIdx.x;
    const int wid  = __builtin_amdgcn_readfirstlane(tid >> 6);
    const int lane = tid & 63;
    const int m = lane & 15, quad = lane >> 4;
    const int row_base = blockIdx.x * 64 + wid * 16;

    // prefetch this lane's 4 A-fragments (k = ks*32 + quad*8) before the barrier
    int r = row_base + m;
    if (r >= NN) r = NN - 1;
    bf16x8 afr[4];
    if constexpr (std::is_same<T, float>::value) {
        const float4* ap = (const float4*)(A + (size_t)r * HD);
        #pragma unroll
        for (int ks = 0; ks < 4; ++ks) {
            float4 x0 = ap[ks * 8 + quad * 2], x1 = ap[ks * 8 + quad * 2 + 1];
            bf16x8 a;
            a[0] = (__bf16)x0.x; a[1] = (__bf16)x0.y; a[2] = (__bf16)x0.z; a[3] = (__bf16)x0.w;
            a[4] = (__bf16)x1.x; a[5] = (__bf16)x1.y; a[6] = (__bf16)x1.z; a[7] = (__bf16)x1.w;
            afr[ks] = a;
        }
    } else {
        const bf16x8* ap = (const bf16x8*)(A + (size_t)r * HD);
        #pragma unroll
        for (int ks = 0; ks < 4; ++ks) afr[ks] = ap[ks * 4 + quad];
    }

    // stage WT -> LDS: 2048 b128 chunks (128 rows x 16 chunks of 8 halfwords)
    #pragma unroll
    for (int it = 0; it < 8; ++it) {
        int id = it * 256 + tid;          // chunk id
        int n = id >> 4, c = id & 15;     // row, 16B-chunk within row
        *(uint4*)&WL[n * WROW + c * 8] = *(const uint4*)(WTg + n * HD + c * 8);
    }
    __syncthreads();

    f32x4 acc[8];
    #pragma unroll
    for (int ct = 0; ct < 8; ++ct) acc[ct] = (f32x4){0.f, 0.f, 0.f, 0.f};

    #pragma unroll
    for (int ks = 0; ks < 4; ++ks) {
        const int k0 = ks * 32 + quad * 8;
        #pragma unroll
        for (int ct = 0; ct < 8; ++ct) {
            bf16x8 bfr = *(const bf16x8*)&WL[(ct * 16 + m) * WROW + k0];
            acc[ct] = __builtin_amdgcn_mfma_f32_16x16x32_bf16(afr[ks], bfr, acc[ct], 0, 0, 0);
        }
    }

    #pragma unroll
    for (int ct = 0; ct < 8; ++ct)
        #pragma unroll
        for (int rr = 0; rr < 4; ++rr) {
            int row = row_base + quad * 4 + rr;
            if (row < NN) HW[(size_t)row * HD + ct * 16 + m] = (__bf16)acc[ct][rr];
        }
}

// ---------------- pull aggregation + epilogue ----------------
// 4 nodes per wave (sequential order), 16 lanes per node; 4-deep software
// pipeline; packed float2 accumulation (v_pk_fma_f32).
// MODE 0: hb = relu(z); MODE 1: hb = relu(z*A+B) + hb; MODE 2: MODE-1 then
// in-register W3 projection -> hw3.

__device__ __forceinline__ void acc8p(f32x2* acc, uint4 rv, float wt) {
    f32x2 w2 = {wt, wt};
    f32x2 x0 = {__uint_as_float(rv.x << 16), __uint_as_float(rv.x & 0xffff0000u)};
    f32x2 x1 = {__uint_as_float(rv.y << 16), __uint_as_float(rv.y & 0xffff0000u)};
    f32x2 x2 = {__uint_as_float(rv.z << 16), __uint_as_float(rv.z & 0xffff0000u)};
    f32x2 x3 = {__uint_as_float(rv.w << 16), __uint_as_float(rv.w & 0xffff0000u)};
    acc[0] = __builtin_elementwise_fma(x0, w2, acc[0]);
    acc[1] = __builtin_elementwise_fma(x1, w2, acc[1]);
    acc[2] = __builtin_elementwise_fma(x2, w2, acc[2]);
    acc[3] = __builtin_elementwise_fma(x3, w2, acc[3]);
}

__device__ __forceinline__ void unpack8(uint4 rv, float* f) {
    f[0] = __uint_as_float(rv.x << 16);         f[1] = __uint_as_float(rv.x & 0xffff0000u);
    f[2] = __uint_as_float(rv.y << 16);         f[3] = __uint_as_float(rv.y & 0xffff0000u);
    f[4] = __uint_as_float(rv.z << 16);         f[5] = __uint_as_float(rv.z & 0xffff0000u);
    f[6] = __uint_as_float(rv.w << 16);         f[7] = __uint_as_float(rv.w & 0xffff0000u);
}

template <int MODE>
__global__ __launch_bounds__(256) void agg_k(const __bf16* __restrict__ hw, const int* __restrict__ rp,
                                             const uint2* __restrict__ edges,
                                             const float* __restrict__ selfn, const float* __restrict__ bias,
                                             const float* __restrict__ bnA, const float* __restrict__ bnB,
                                             __bf16* __restrict__ hb, const float* __restrict__ W3,
                                             float2* __restrict__ hw3) {
    const int lane = threadIdx.x & 63;
    const int wid  = threadIdx.x >> 6;
    const int grp  = lane >> 4;     // node within the wave
    const int m    = lane & 15;     // 16B chunk within the row (channels 8m..8m+7)
    const int n = blockIdx.x * 16 + wid * 4 + grp;   // NN = 6250*16 exactly
    const int c0 = m * 8;
    const int L = NE - 1;

    const int e0 = rp[n], e1 = rp[n + 1];

    // issue long-latency independent loads first: self row, residual row
    const float sn = selfn[n];
    uint4 rv_self = *(const uint4*)(hw + ((size_t)n << 7) + c0);
    __bf16* hbp = hb + ((size_t)n << 7) + c0;
    uint4 rv_prev;
    if (MODE != 0) rv_prev = *(const uint4*)hbp;

    f32x2 acc2[4];
    #pragma unroll
    for (int j = 0; j < 4; ++j) acc2[j] = (f32x2){0.f, 0.f};

    // 4-deep pipelined gather loop
    int e = e0;
    int cnt = e1 - e0;
    uint2 edA = edges[min(e,     L)];
    uint2 edB = edges[min(e + 1, L)];
    uint2 edC = edges[min(e + 2, L)];
    uint2 edD = edges[min(e + 3, L)];
    while (cnt >= 4) {
        uint4 r0 = *(const uint4*)(hw + ((size_t)edA.x << 7) + c0);
        uint4 r1 = *(const uint4*)(hw + ((size_t)edB.x << 7) + c0);
        uint4 r2 = *(const uint4*)(hw + ((size_t)edC.x << 7) + c0);
        uint4 r3 = *(const uint4*)(hw + ((size_t)edD.x << 7) + c0);
        uint2 nA = edges[min(e + 4, L)];
        uint2 nB = edges[min(e + 5, L)];
        uint2 nC = edges[min(e + 6, L)];
        uint2 nD = edges[min(e + 7, L)];
        acc8p(acc2, r0, __uint_as_float(edA.y));
        acc8p(acc2, r1, __uint_as_float(edB.y));
        acc8p(acc2, r2, __uint_as_float(edC.y));
        acc8p(acc2, r3, __uint_as_float(edD.y));
        edA = nA; edB = nB; edC = nC; edD = nD;
        e += 4; cnt -= 4;
    }
    if (cnt >= 2) {
        uint4 r0 = *(const uint4*)(hw + ((size_t)edA.x << 7) + c0);
        uint4 r1 = *(const uint4*)(hw + ((size_t)edB.x << 7) + c0);
        acc8p(acc2, r0, __uint_as_float(edA.y));
        acc8p(acc2, r1, __uint_as_float(edB.y));
        edA = edC;           // for the cnt==3 tail
        cnt -= 2;
    }
    if (cnt == 1) {
        uint4 rv = *(const uint4*)(hw + ((size_t)edA.x << 7) + c0);
        acc8p(acc2, rv, __uint_as_float(edA.y));
    }
    acc8p(acc2, rv_self, sn);   // self-loop

    float acc[8] = {acc2[0][0], acc2[0][1], acc2[1][0], acc2[1][1],
                    acc2[2][0], acc2[2][1], acc2[3][0], acc2[3][1]};

    float4 bs0 = *(const float4*)(bias + c0);
    float4 bs1 = *(const float4*)(bias + c0 + 4);
    float z[8] = {acc[0] + bs0.x, acc[1] + bs0.y, acc[2] + bs0.z, acc[3] + bs0.w,
                  acc[4] + bs1.x, acc[5] + bs1.y, acc[6] + bs1.z, acc[7] + bs1.w};

    if (MODE == 0) {
        bf16x8 v;
        #pragma unroll
        for (int j = 0; j < 8; ++j) v[j] = (__bf16)fmaxf(z[j], 0.f);
        *(bf16x8*)hbp = v;
    } else {
        float4 a0v = *(const float4*)(bnA + c0), a1v = *(const float4*)(bnA + c0 + 4);
        float4 b0v = *(const float4*)(bnB + c0), b1v = *(const float4*)(bnB + c0 + 4);
        float Af[8] = {a0v.x, a0v.y, a0v.z, a0v.w, a1v.x, a1v.y, a1v.z, a1v.w};
        float Bf[8] = {b0v.x, b0v.y, b0v.z, b0v.w, b1v.x, b1v.y, b1v.z, b1v.w};
        float pr[8];
        unpack8(rv_prev, pr);
        float hn[8];
        #pragma unroll
        for (int j = 0; j < 8; ++j)
            hn[j] = fmaxf(fmaf(z[j], Af[j], Bf[j]), 0.f) + pr[j];

        if (MODE == 1) {
            bf16x8 v;
            #pragma unroll
            for (int j = 0; j < 8; ++j) v[j] = (__bf16)hn[j];
            *(bf16x8*)hbp = v;
        } else {
            // fused output projection: hw3[n] = hn . W3  (W3 is [128,2] row-major)
            float4 w0 = *(const float4*)(W3 + c0 * 2);
            float4 w1 = *(const float4*)(W3 + c0 * 2 + 4);
            float4 w2 = *(const float4*)(W3 + c0 * 2 + 8);
            float4 w3v = *(const float4*)(W3 + c0 * 2 + 12);
            float p0 = hn[0] * w0.x + hn[1] * w0.z + hn[2] * w1.x + hn[3] * w1.z
                     + hn[4] * w2.x + hn[5] * w2.z + hn[6] * w3v.x + hn[7] * w3v.z;
            float p1 = hn[0] * w0.y + hn[1] * w0.w + hn[2] * w1.y + hn[3] * w1.w
                     + hn[4] * w2.y + hn[5] * w2.w + hn[6] * w3v.y + hn[7] * w3v.w;
            // reduce within the 16-lane group (xor < 16 stays inside the group)
            #pragma unroll
            for (int o = 1; o < 16; o <<= 1) {
                p0 += __shfl_xor(p0, o);
                p1 += __shfl_xor(p1, o);
            }
            if (m == 0) hw3[n] = make_float2(p0, p1);
        }
    }
}

// ---------------- final: aggregate hw3 + log_softmax ----------------

__global__ __launch_bounds__(256) void final_k(const float2* __restrict__ hw3, const int* __restrict__ rp,
                                               const uint2* __restrict__ edges,
                                               const float* __restrict__ selfn, const float* __restrict__ b3,
                                               float* __restrict__ out) {
    int n = blockIdx.x * 256 + threadIdx.x;
    if (n >= NN) return;
    const int L = NE - 1;
    float a0 = 0.f, a1 = 0.f;
    int e0 = rp[n], e1 = rp[n + 1];
    int cnt = e1 - e0;
    // 2-deep pipelined gather
    uint2 edA = edges[min(e0,     L)];
    uint2 edB = edges[min(e0 + 1, L)];
    int e = e0;
    while (cnt >= 2) {
        float2 v0 = hw3[edA.x];
        float2 v1 = hw3[edB.x];
        float w0 = __uint_as_float(edA.y), w1 = __uint_as_float(edB.y);
        edA = edges[min(e + 2, L)];
        edB = edges[min(e + 3, L)];
        a0 = fmaf(w0, v0.x, a0); a1 = fmaf(w0, v0.y, a1);
        a0 = fmaf(w1, v1.x, a0); a1 = fmaf(w1, v1.y, a1);
        e += 2; cnt -= 2;
    }
    if (cnt == 1) {
        float2 v = hw3[edA.x];
        float w = __uint_as_float(edA.y);
        a0 = fmaf(w, v.x, a0); a1 = fmaf(w, v.y, a1);
    }
    float sn = selfn[n];
    float2 hv = hw3[n];
    float z0 = a0 + sn * hv.x + b3[0];
    float z1 = a1 + sn * hv.y + b3[1];
    float mx = fmaxf(z0, z1);
    float l = mx + logf(expf(z0 - mx) + expf(z1 - mx));
    out[n * 2 + 0] = z0 - l;
    out[n * 2 + 1] = z1 - l;
}

// ---------------- launch ----------------

extern "C" void kernel_launch(void* const* d_in, const int* in_sizes, int n_in,
                              void* d_out, int out_size, void* d_ws, size_t ws_size,
                              hipStream_t stream) {
    (void)in_sizes; (void)n_in; (void)out_size; (void)ws_size;

    const float* x   = (const float*)d_in[0];
    const int*   ei  = (const int*)d_in[1];
    const float* W0  = (const float*)d_in[2];
    const float* b0  = (const float*)d_in[3];
    const float* W1  = (const float*)d_in[4];
    const float* b1  = (const float*)d_in[5];
    const float* W2  = (const float*)d_in[6];
    const float* b2  = (const float*)d_in[7];
    const float* W3  = (const float*)d_in[8];
    const float* b3  = (const float*)d_in[9];
    const float* bn0g = (const float*)d_in[10];
    const float* bn0b = (const float*)d_in[11];
    const float* bn0m = (const float*)d_in[12];
    const float* bn0v = (const float*)d_in[13];
    const float* bn1g = (const float*)d_in[14];
    const float* bn1b = (const float*)d_in[15];
    const float* bn1m = (const float*)d_in[16];
    const float* bn1v = (const float*)d_in[17];
    float* out = (float*)d_out;

    char* p = (char*)d_ws;
    auto alloc = [&](size_t bytes) -> void* {
        void* r = (void*)p;
        p += (bytes + 255) & ~(size_t)255;
        return r;
    };
    __bf16*  hb    = (__bf16*)alloc((size_t)NN * HD * 2);   // h in bf16
    __bf16*  hw    = (__bf16*)alloc((size_t)NN * HD * 2);
    float2*  hw3   = (float2*)alloc((size_t)NN * 8);
    float*   dis   = (float*)alloc((size_t)NN * 4);
    float*   selfn = (float*)alloc((size_t)NN * 4);
    int*     count = (int*)alloc((size_t)NN * 4);
    int*     rp    = (int*)alloc((size_t)(NN + 1) * 4);
    uint2*   edges = (uint2*)alloc((size_t)NE * 8);
    int*     rank  = (int*)alloc((size_t)NE * 4);
    int*     bsums = (int*)alloc((size_t)512 * 4);
    float*   bnA0  = (float*)alloc(128 * 4);
    float*   bnB0  = (float*)alloc(128 * 4);
    float*   bnA1  = (float*)alloc(128 * 4);
    float*   bnB1  = (float*)alloc(128 * 4);
    __bf16*  WT    = (__bf16*)alloc((size_t)3 * HD * HD * 2);  // transposed bf16 weights

    const int NB_E = (NE + 255) / 256;   // 3125
    const int NB_N = (NN + 255) / 256;   // 391
    const int NB_G = (NN + 63) / 64;     // 1563 (GEMM: 64 rows/block)
    const int NB_A = (NN + 15) / 16;     // 6250 (agg: 16 nodes per block)

    hipMemsetAsync(count, 0, (size_t)NN * 4, stream);

    count_k<<<NB_E, 256, 0, stream>>>(ei, count, rank);
    prep_k<<<4, 256, 0, stream>>>(W0, W1, W2, WT,
                                  bn0g, bn0b, bn0m, bn0v, bn1g, bn1b, bn1m, bn1v,
                                  bnA0, bnB0, bnA1, bnB1);
    scan1_k<<<NB_N, 256, 0, stream>>>(count, rp, bsums, dis, selfn);
    scan23_k<<<NB_N, 256, 0, stream>>>(rp, bsums, NB_N);
    scatter_k<<<NB_E, 256, 0, stream>>>(ei, rp, rank, dis, edges);

    // layer 0: hb = relu(conv(x, W0, b0))
    gemm128_k<float><<<NB_G, 256, 0, stream>>>(x, WT, hw);
    agg_k<0><<<NB_A, 256, 0, stream>>>(hw, rp, edges, selfn, b0,
                                       nullptr, nullptr, hb, nullptr, nullptr);
    // layer 1: hb = relu(bn0(conv(hb, W1, b1))) + hb
    gemm128_k<__bf16><<<NB_G, 256, 0, stream>>>(hb, WT + HD * HD, hw);
    agg_k<1><<<NB_A, 256, 0, stream>>>(hw, rp, edges, selfn, b1,
                                       bnA0, bnB0, hb, nullptr, nullptr);
    // layer 2 (+ fused W3 projection): hw3 = (relu(bn1(conv(hb, W2, b2))) + hb) @ W3
    gemm128_k<__bf16><<<NB_G, 256, 0, stream>>>(hb, WT + 2 * HD * HD, hw);
    agg_k<2><<<NB_A, 256, 0, stream>>>(hw, rp, edges, selfn, b2,
                                       bnA1, bnB1, hb, W3, hw3);
    // final aggregation + log_softmax
    final_k<<<NB_N, 256, 0, stream>>>(hw3, rp, edges, selfn, b3, out);
}